// Round 1
// baseline (988.155 us; speedup 1.0000x reference)
//
#include <hip/hip_runtime.h>
#include <hip/hip_bf16.h>

#define TPB 256

// ---------------- CSR build ----------------

__global__ void count_kernel(const int* __restrict__ dst, int E, int* __restrict__ cnt) {
    int e = blockIdx.x * blockDim.x + threadIdx.x;
    if (e < E) atomicAdd(&cnt[dst[e]], 1);
}

__global__ void dinv_kernel(const int* __restrict__ cnt, int n, float* __restrict__ dinv) {
    int i = blockIdx.x * blockDim.x + threadIdx.x;
    if (i < n) dinv[i] = rsqrtf((float)cnt[i] + 1.0f);
}

// single-block chunked exclusive scan of cnt[0..n) -> off[0..n], also cur = off
__global__ void scan_kernel(const int* __restrict__ cnt, int* __restrict__ off,
                            int* __restrict__ cur, int n) {
    __shared__ int sdata[1024];
    __shared__ int running;
    if (threadIdx.x == 0) running = 0;
    __syncthreads();
    for (int base = 0; base < n; base += 1024) {
        int i = base + (int)threadIdx.x;
        int v = (i < n) ? cnt[i] : 0;
        sdata[threadIdx.x] = v;
        __syncthreads();
        for (int s = 1; s < 1024; s <<= 1) {
            int t = (threadIdx.x >= (unsigned)s) ? sdata[threadIdx.x - s] : 0;
            __syncthreads();
            sdata[threadIdx.x] += t;
            __syncthreads();
        }
        int incl = sdata[threadIdx.x];
        int total = sdata[1023];
        int excl = incl - v;
        int o = running + excl;
        if (i < n) { off[i] = o; cur[i] = o; }
        __syncthreads();
        if (threadIdx.x == 0) running += total;
        __syncthreads();
    }
    if (threadIdx.x == 0) off[n] = running;
}

__global__ void fill_kernel(const int* __restrict__ src, const int* __restrict__ dst, int E,
                            int* __restrict__ cur, int* __restrict__ col) {
    int e = blockIdx.x * blockDim.x + threadIdx.x;
    if (e < E) {
        int p = atomicAdd(&cur[dst[e]], 1);
        col[p] = src[e];
    }
}

// ---------------- dense matmul: Y[n,COUT] = X[n,CIN] @ W[CIN,COUT] ----------------

template <int CIN, int COUT>
__global__ void matmul_kernel(const float* __restrict__ X, const float* __restrict__ W,
                              float* __restrict__ Y, int n) {
    __shared__ float Wl[CIN * COUT];
    for (int idx = threadIdx.x; idx < CIN * COUT; idx += blockDim.x) Wl[idx] = W[idx];
    __syncthreads();
    int tid = blockIdx.x * blockDim.x + threadIdx.x;
    int node = tid / COUT;
    int c = tid % COUT;
    if (node >= n) return;
    const float* xr = X + (size_t)node * CIN;
    float acc = 0.f;
#pragma unroll
    for (int k = 0; k < CIN; k++) acc += xr[k] * Wl[k * COUT + c];
    Y[tid] = acc;
}

// ---------------- GCN aggregation (gather over CSR-by-dst) ----------------
// out[i,c] = dinv_i * sum_{j in N_in(i)} dinv_j * HW[j,c] + dinv_i^2 * HW[i,c] + b[c]

template <int C, bool RELU>
__global__ void agg_kernel(const float* __restrict__ HW, const int* __restrict__ off,
                           const int* __restrict__ col, const float* __restrict__ dinv,
                           const float* __restrict__ bias, float* __restrict__ out, int n) {
    int tid = blockIdx.x * blockDim.x + threadIdx.x;
    int node = tid / C;
    int c = tid % C;
    if (node >= n) return;
    int s = off[node], e = off[node + 1];
    float acc = 0.f;
    for (int p = s; p < e; p++) {
        int j = col[p];
        acc += dinv[j] * HW[(size_t)j * C + c];
    }
    float di = dinv[node];
    float v = di * acc + di * di * HW[(size_t)node * C + c] + bias[c];
    if (RELU) v = fmaxf(v, 0.f);
    out[tid] = v;
}

// ---------------- attention pooling ----------------

__global__ void colsum_kernel(const float* __restrict__ H, int n, float* __restrict__ colsum) {
    int c = threadIdx.x % 16;
    int w = (blockIdx.x * blockDim.x + threadIdx.x) / 16;
    int stride = (gridDim.x * blockDim.x) / 16;
    float acc = 0.f;
    for (int node = w; node < n; node += stride) acc += H[(size_t)node * 16 + c];
    __shared__ float sdata[TPB];
    sdata[threadIdx.x] = acc;
    __syncthreads();
    if (threadIdx.x < 16) {
        float s = 0.f;
        for (int t = threadIdx.x; t < TPB; t += 16) s += sdata[t];
        atomicAdd(&colsum[threadIdx.x], s);
    }
}

__global__ void cvec_kernel(const float* __restrict__ colsum, const float* __restrict__ Wa,
                            float n_inv, float* __restrict__ cvec) {
    int j = threadIdx.x;
    if (j < 16) {
        float acc = 0.f;
        for (int i = 0; i < 16; i++) acc += (colsum[i] * n_inv) * Wa[i * 16 + j];
        cvec[j] = tanhf(acc);
    }
}

__global__ void pool_kernel(const float* __restrict__ H, int n, const float* __restrict__ cvec,
                            float* __restrict__ rep) {
    int c = threadIdx.x % 16;
    float cv = cvec[c];
    int w = (blockIdx.x * blockDim.x + threadIdx.x) / 16;
    int stride = (gridDim.x * blockDim.x) / 16;
    float acc = 0.f;
    for (int node = w; node < n; node += stride) {
        float x = H[(size_t)node * 16 + c];
        float p = x * cv;
        p += __shfl_xor(p, 1, 16);
        p += __shfl_xor(p, 2, 16);
        p += __shfl_xor(p, 4, 16);
        p += __shfl_xor(p, 8, 16);
        float s = 1.f / (1.f + __expf(-p));
        acc += s * x;
    }
    __shared__ float sdata[TPB];
    sdata[threadIdx.x] = acc;
    __syncthreads();
    if (threadIdx.x < 16) {
        float s = 0.f;
        for (int t = threadIdx.x; t < TPB; t += 16) s += sdata[t];
        atomicAdd(&rep[threadIdx.x], s);
    }
}

// ---------------- final tensor-network scoring ----------------

__global__ void final_kernel(const float* __restrict__ e1, const float* __restrict__ e2,
                             const float* __restrict__ Wt, const float* __restrict__ Wb,
                             const float* __restrict__ bt, const float* __restrict__ Wfc,
                             const float* __restrict__ bfc, const float* __restrict__ Wsc,
                             const float* __restrict__ bsc, float* __restrict__ out) {
    __shared__ float scores[16], tvec[16], se1[16], se2[16];
    int t = threadIdx.x;
    if (t < 16) { se1[t] = e1[t]; se2[t] = e2[t]; }
    __syncthreads();
    if (t < 16) {
        float bil = 0.f;
        for (int i = 0; i < 16; i++) {
            float a = se1[i];
            for (int j = 0; j < 16; j++) bil += a * se2[j] * Wt[(i * 16 + j) * 16 + t];
        }
        float blk = 0.f;
        for (int m = 0; m < 16; m++)
            blk += Wb[t * 32 + m] * se1[m] + Wb[t * 32 + 16 + m] * se2[m];
        scores[t] = fmaxf(bil + blk + bt[t], 0.f);
    }
    __syncthreads();
    if (t < 16) {
        float acc = bfc[t];
        for (int k = 0; k < 16; k++) acc += scores[k] * Wfc[k * 16 + t];
        tvec[t] = tanhf(acc);
    }
    __syncthreads();
    if (t == 0) {
        float acc = bsc[0];
        for (int j = 0; j < 16; j++) acc += tvec[j] * Wsc[j];
        out[0] = 1.f / (1.f + __expf(-acc));
    }
}

// ---------------- launcher ----------------

extern "C" void kernel_launch(void* const* d_in, const int* in_sizes, int n_in,
                              void* d_out, int out_size, void* d_ws, size_t ws_size,
                              hipStream_t stream) {
    const float* X1 = (const float*)d_in[0];
    const float* X2 = (const float*)d_in[1];
    const int* edges1 = (const int*)d_in[2];
    const int* edges2 = (const int*)d_in[3];
    const float* W1 = (const float*)d_in[4];
    const float* b1 = (const float*)d_in[5];
    const float* W2 = (const float*)d_in[6];
    const float* b2 = (const float*)d_in[7];
    const float* W3 = (const float*)d_in[8];
    const float* b3 = (const float*)d_in[9];
    const float* Wa = (const float*)d_in[10];
    const float* Wt = (const float*)d_in[11];
    const float* Wb = (const float*)d_in[12];
    const float* bt = (const float*)d_in[13];
    const float* Wfc = (const float*)d_in[14];
    const float* bfc = (const float*)d_in[15];
    const float* Wsc = (const float*)d_in[16];
    const float* bsc = (const float*)d_in[17];
    float* out = (float*)d_out;

    const int N = in_sizes[0] / 96;
    const int E = in_sizes[2] / 2;

    // workspace layout (16B aligned chunks)
    char* ws = (char*)d_ws;
    size_t o = 0;
    auto alloc = [&](size_t bytes) {
        void* p = ws + o;
        o += (bytes + 255) & ~(size_t)255;
        return p;
    };
    int* cnt = (int*)alloc((size_t)N * 4);
    int* off = (int*)alloc((size_t)(N + 1) * 4);
    int* cur = (int*)alloc((size_t)N * 4);
    int* col = (int*)alloc((size_t)E * 4);
    float* dinv = (float*)alloc((size_t)N * 4);
    float* small = (float*)alloc(96 * 4);  // colsum(16) cvec(16) rep1(16) [pad] rep2(16)
    float* colsum = small;
    float* cvec = small + 16;
    float* rep1 = small + 32;
    float* rep2 = small + 48;
    float* bufA = (float*)alloc((size_t)N * 64 * 4);
    float* bufB = (float*)alloc((size_t)N * 64 * 4);

    const int gE = (E + TPB - 1) / TPB;
    const int gN = (N + TPB - 1) / TPB;

    hipMemsetAsync(small, 0, 96 * 4, stream);

    const float* Xs[2] = {X1, X2};
    const int* Es[2] = {edges1, edges2};
    float* reps[2] = {rep1, rep2};

    for (int g = 0; g < 2; g++) {
        const int* src = Es[g];
        const int* dst = Es[g] + E;

        hipMemsetAsync(cnt, 0, (size_t)N * 4, stream);
        if (g == 1) hipMemsetAsync(colsum, 0, 16 * 4, stream);

        count_kernel<<<gE, TPB, 0, stream>>>(dst, E, cnt);
        dinv_kernel<<<gN, TPB, 0, stream>>>(cnt, N, dinv);
        scan_kernel<<<1, 1024, 0, stream>>>(cnt, off, cur, N);
        fill_kernel<<<gE, TPB, 0, stream>>>(src, dst, E, cur, col);

        // layer 1: 96 -> 64, relu
        matmul_kernel<96, 64><<<((size_t)N * 64 + TPB - 1) / TPB, TPB, 0, stream>>>(Xs[g], W1, bufA, N);
        agg_kernel<64, true><<<((size_t)N * 64 + TPB - 1) / TPB, TPB, 0, stream>>>(bufA, off, col, dinv, b1, bufB, N);
        // layer 2: 64 -> 32, relu
        matmul_kernel<64, 32><<<((size_t)N * 32 + TPB - 1) / TPB, TPB, 0, stream>>>(bufB, W2, bufA, N);
        agg_kernel<32, true><<<((size_t)N * 32 + TPB - 1) / TPB, TPB, 0, stream>>>(bufA, off, col, dinv, b2, bufB, N);
        // layer 3: 32 -> 16, no relu
        matmul_kernel<32, 16><<<((size_t)N * 16 + TPB - 1) / TPB, TPB, 0, stream>>>(bufB, W3, bufA, N);
        agg_kernel<16, false><<<((size_t)N * 16 + TPB - 1) / TPB, TPB, 0, stream>>>(bufA, off, col, dinv, b3, bufB, N);

        // attention pooling
        colsum_kernel<<<256, TPB, 0, stream>>>(bufB, N, colsum);
        cvec_kernel<<<1, 64, 0, stream>>>(colsum, Wa, 1.0f / (float)N, cvec);
        pool_kernel<<<256, TPB, 0, stream>>>(bufB, N, cvec, reps[g]);
    }

    final_kernel<<<1, 64, 0, stream>>>(rep1, rep2, Wt, Wb, bt, Wfc, bfc, Wsc, bsc, out);
}

// Round 2
// 819.534 us; speedup vs baseline: 1.2058x; 1.2058x over previous
//
#include <hip/hip_runtime.h>
#include <hip/hip_bf16.h>

#define TPB 256

// ---------------- CSR build ----------------

__global__ void count_kernel(const int* __restrict__ dst, int E, int* __restrict__ cnt) {
    int e = blockIdx.x * blockDim.x + threadIdx.x;
    if (e < E) atomicAdd(&cnt[dst[e]], 1);
}

// Phase 1: per-block (1024-element chunk) local exclusive scan + block totals.
// Also computes dinv[i] = rsqrt(cnt[i]+1) since cnt is already in registers.
__global__ void scan1_kernel(const int* __restrict__ cnt, int n,
                             int* __restrict__ off, int* __restrict__ bsum,
                             float* __restrict__ dinv) {
    __shared__ int tsum[TPB];
    int base = blockIdx.x * 1024;
    int i0 = base + (int)threadIdx.x * 4;
    int vals[4];
    int s = 0;
#pragma unroll
    for (int k = 0; k < 4; k++) {
        int i = i0 + k;
        vals[k] = (i < n) ? cnt[i] : 0;
        s += vals[k];
    }
    tsum[threadIdx.x] = s;
    __syncthreads();
    for (int st = 1; st < TPB; st <<= 1) {
        int t = (threadIdx.x >= (unsigned)st) ? tsum[threadIdx.x - st] : 0;
        __syncthreads();
        tsum[threadIdx.x] += t;
        __syncthreads();
    }
    int running = tsum[threadIdx.x] - s;  // exclusive base for this thread
#pragma unroll
    for (int k = 0; k < 4; k++) {
        int i = i0 + k;
        if (i < n) {
            off[i] = running;
            dinv[i] = rsqrtf((float)vals[k] + 1.0f);
        }
        running += vals[k];
    }
    if (threadIdx.x == TPB - 1) bsum[blockIdx.x] = tsum[TPB - 1];
}

// Phase 2: one wave exclusive-scans the block totals (nb <= 64), writes grand total.
__global__ void scan2_kernel(int* __restrict__ bsum, int nb, int* __restrict__ offN) {
    int t = threadIdx.x;  // 64 threads
    int orig = (t < nb) ? bsum[t] : 0;
    int v = orig;
    for (int d = 1; d < 64; d <<= 1) {
        int u = __shfl_up(v, d, 64);
        if (t >= d) v += u;
    }
    int total = __shfl(v, 63, 64);
    if (t < nb) bsum[t] = v - orig;  // exclusive
    if (t == 0) offN[0] = total;
}

// Phase 3: add block bases; produce final off and cur.
__global__ void scan3_kernel(int* __restrict__ off, int* __restrict__ cur,
                             const int* __restrict__ bsum, int n) {
    int i = blockIdx.x * blockDim.x + threadIdx.x;
    if (i < n) {
        int v = off[i] + bsum[i >> 10];
        off[i] = v;
        cur[i] = v;
    }
}

__global__ void fill_kernel(const int* __restrict__ src, const int* __restrict__ dst, int E,
                            int* __restrict__ cur, int* __restrict__ col) {
    int e = blockIdx.x * blockDim.x + threadIdx.x;
    if (e < E) {
        int p = atomicAdd(&cur[dst[e]], 1);
        col[p] = src[e];
    }
}

// ---------------- dense matmul: Y[n,COUT] = X[n,CIN] @ W[CIN,COUT] ----------------

template <int CIN, int COUT>
__global__ void matmul_kernel(const float* __restrict__ X, const float* __restrict__ W,
                              float* __restrict__ Y, int n) {
    __shared__ float Wl[CIN * COUT];
    for (int idx = threadIdx.x; idx < CIN * COUT; idx += blockDim.x) Wl[idx] = W[idx];
    __syncthreads();
    int tid = blockIdx.x * blockDim.x + threadIdx.x;
    int node = tid / COUT;
    int c = tid % COUT;
    if (node >= n) return;
    const float* xr = X + (size_t)node * CIN;
    float acc = 0.f;
#pragma unroll
    for (int k = 0; k < CIN; k++) acc += xr[k] * Wl[k * COUT + c];
    Y[tid] = acc;
}

// ---------------- GCN aggregation (gather over CSR-by-dst) ----------------
// out[i,c] = dinv_i * sum_{j in N_in(i)} dinv_j * HW[j,c] + dinv_i^2 * HW[i,c] + b[c]

template <int C, bool RELU>
__global__ void agg_kernel(const float* __restrict__ HW, const int* __restrict__ off,
                           const int* __restrict__ col, const float* __restrict__ dinv,
                           const float* __restrict__ bias, float* __restrict__ out, int n) {
    int tid = blockIdx.x * blockDim.x + threadIdx.x;
    int node = tid / C;
    int c = tid % C;
    if (node >= n) return;
    int s = off[node], e = off[node + 1];
    float acc = 0.f;
    for (int p = s; p < e; p++) {
        int j = col[p];
        acc += dinv[j] * HW[(size_t)j * C + c];
    }
    float di = dinv[node];
    float v = di * acc + di * di * HW[(size_t)node * C + c] + bias[c];
    if (RELU) v = fmaxf(v, 0.f);
    out[tid] = v;
}

// ---------------- attention pooling ----------------

__global__ void colsum_kernel(const float* __restrict__ H, int n, float* __restrict__ colsum) {
    int c = threadIdx.x % 16;
    int w = (blockIdx.x * blockDim.x + threadIdx.x) / 16;
    int stride = (gridDim.x * blockDim.x) / 16;
    float acc = 0.f;
    for (int node = w; node < n; node += stride) acc += H[(size_t)node * 16 + c];
    __shared__ float sdata[TPB];
    sdata[threadIdx.x] = acc;
    __syncthreads();
    if (threadIdx.x < 16) {
        float s = 0.f;
        for (int t = threadIdx.x; t < TPB; t += 16) s += sdata[t];
        atomicAdd(&colsum[threadIdx.x], s);
    }
}

__global__ void cvec_kernel(const float* __restrict__ colsum, const float* __restrict__ Wa,
                            float n_inv, float* __restrict__ cvec) {
    int j = threadIdx.x;
    if (j < 16) {
        float acc = 0.f;
        for (int i = 0; i < 16; i++) acc += (colsum[i] * n_inv) * Wa[i * 16 + j];
        cvec[j] = tanhf(acc);
    }
}

__global__ void pool_kernel(const float* __restrict__ H, int n, const float* __restrict__ cvec,
                            float* __restrict__ rep) {
    int c = threadIdx.x % 16;
    float cv = cvec[c];
    int w = (blockIdx.x * blockDim.x + threadIdx.x) / 16;
    int stride = (gridDim.x * blockDim.x) / 16;
    float acc = 0.f;
    for (int node = w; node < n; node += stride) {
        float x = H[(size_t)node * 16 + c];
        float p = x * cv;
        p += __shfl_xor(p, 1, 16);
        p += __shfl_xor(p, 2, 16);
        p += __shfl_xor(p, 4, 16);
        p += __shfl_xor(p, 8, 16);
        float s = 1.f / (1.f + __expf(-p));
        acc += s * x;
    }
    __shared__ float sdata[TPB];
    sdata[threadIdx.x] = acc;
    __syncthreads();
    if (threadIdx.x < 16) {
        float s = 0.f;
        for (int t = threadIdx.x; t < TPB; t += 16) s += sdata[t];
        atomicAdd(&rep[threadIdx.x], s);
    }
}

// ---------------- final tensor-network scoring ----------------

__global__ void final_kernel(const float* __restrict__ e1, const float* __restrict__ e2,
                             const float* __restrict__ Wt, const float* __restrict__ Wb,
                             const float* __restrict__ bt, const float* __restrict__ Wfc,
                             const float* __restrict__ bfc, const float* __restrict__ Wsc,
                             const float* __restrict__ bsc, float* __restrict__ out) {
    __shared__ float scores[16], tvec[16], se1[16], se2[16];
    int t = threadIdx.x;
    if (t < 16) { se1[t] = e1[t]; se2[t] = e2[t]; }
    __syncthreads();
    if (t < 16) {
        float bil = 0.f;
        for (int i = 0; i < 16; i++) {
            float a = se1[i];
            for (int j = 0; j < 16; j++) bil += a * se2[j] * Wt[(i * 16 + j) * 16 + t];
        }
        float blk = 0.f;
        for (int m = 0; m < 16; m++)
            blk += Wb[t * 32 + m] * se1[m] + Wb[t * 32 + 16 + m] * se2[m];
        scores[t] = fmaxf(bil + blk + bt[t], 0.f);
    }
    __syncthreads();
    if (t < 16) {
        float acc = bfc[t];
        for (int k = 0; k < 16; k++) acc += scores[k] * Wfc[k * 16 + t];
        tvec[t] = tanhf(acc);
    }
    __syncthreads();
    if (t == 0) {
        float acc = bsc[0];
        for (int j = 0; j < 16; j++) acc += tvec[j] * Wsc[j];
        out[0] = 1.f / (1.f + __expf(-acc));
    }
}

// ---------------- launcher ----------------

extern "C" void kernel_launch(void* const* d_in, const int* in_sizes, int n_in,
                              void* d_out, int out_size, void* d_ws, size_t ws_size,
                              hipStream_t stream) {
    const float* X1 = (const float*)d_in[0];
    const float* X2 = (const float*)d_in[1];
    const int* edges1 = (const int*)d_in[2];
    const int* edges2 = (const int*)d_in[3];
    const float* W1 = (const float*)d_in[4];
    const float* b1 = (const float*)d_in[5];
    const float* W2 = (const float*)d_in[6];
    const float* b2 = (const float*)d_in[7];
    const float* W3 = (const float*)d_in[8];
    const float* b3 = (const float*)d_in[9];
    const float* Wa = (const float*)d_in[10];
    const float* Wt = (const float*)d_in[11];
    const float* Wb = (const float*)d_in[12];
    const float* bt = (const float*)d_in[13];
    const float* Wfc = (const float*)d_in[14];
    const float* bfc = (const float*)d_in[15];
    const float* Wsc = (const float*)d_in[16];
    const float* bsc = (const float*)d_in[17];
    float* out = (float*)d_out;

    const int N = in_sizes[0] / 96;
    const int E = in_sizes[2] / 2;
    const int NB = (N + 1023) / 1024;  // scan chunks (49 for N=50000; must be <= 64)

    // workspace layout (256B aligned chunks)
    char* ws = (char*)d_ws;
    size_t o = 0;
    auto alloc = [&](size_t bytes) {
        void* p = ws + o;
        o += (bytes + 255) & ~(size_t)255;
        return p;
    };
    int* cnt = (int*)alloc((size_t)N * 4);
    int* off = (int*)alloc((size_t)(N + 1) * 4);
    int* cur = (int*)alloc((size_t)N * 4);
    int* col = (int*)alloc((size_t)E * 4);
    int* bsum = (int*)alloc((size_t)64 * 4);
    float* dinv = (float*)alloc((size_t)N * 4);
    float* small = (float*)alloc(96 * 4);  // colsum(16) cvec(16) rep1(16) rep2(16)
    float* colsum = small;
    float* cvec = small + 16;
    float* rep1 = small + 32;
    float* rep2 = small + 48;
    float* bufA = (float*)alloc((size_t)N * 64 * 4);
    float* bufB = (float*)alloc((size_t)N * 64 * 4);

    const int gE = (E + TPB - 1) / TPB;
    const int gN = (N + TPB - 1) / TPB;

    hipMemsetAsync(small, 0, 96 * 4, stream);

    const float* Xs[2] = {X1, X2};
    const int* Es[2] = {edges1, edges2};
    float* reps[2] = {rep1, rep2};

    for (int g = 0; g < 2; g++) {
        const int* src = Es[g];
        const int* dst = Es[g] + E;

        hipMemsetAsync(cnt, 0, (size_t)N * 4, stream);
        if (g == 1) hipMemsetAsync(colsum, 0, 16 * 4, stream);

        count_kernel<<<gE, TPB, 0, stream>>>(dst, E, cnt);
        scan1_kernel<<<NB, TPB, 0, stream>>>(cnt, N, off, bsum, dinv);
        scan2_kernel<<<1, 64, 0, stream>>>(bsum, NB, off + N);
        scan3_kernel<<<gN, TPB, 0, stream>>>(off, cur, bsum, N);
        fill_kernel<<<gE, TPB, 0, stream>>>(src, dst, E, cur, col);

        // layer 1: 96 -> 64, relu
        matmul_kernel<96, 64><<<((size_t)N * 64 + TPB - 1) / TPB, TPB, 0, stream>>>(Xs[g], W1, bufA, N);
        agg_kernel<64, true><<<((size_t)N * 64 + TPB - 1) / TPB, TPB, 0, stream>>>(bufA, off, col, dinv, b1, bufB, N);
        // layer 2: 64 -> 32, relu
        matmul_kernel<64, 32><<<((size_t)N * 32 + TPB - 1) / TPB, TPB, 0, stream>>>(bufB, W2, bufA, N);
        agg_kernel<32, true><<<((size_t)N * 32 + TPB - 1) / TPB, TPB, 0, stream>>>(bufA, off, col, dinv, b2, bufB, N);
        // layer 3: 32 -> 16, no relu
        matmul_kernel<32, 16><<<((size_t)N * 16 + TPB - 1) / TPB, TPB, 0, stream>>>(bufB, W3, bufA, N);
        agg_kernel<16, false><<<((size_t)N * 16 + TPB - 1) / TPB, TPB, 0, stream>>>(bufA, off, col, dinv, b3, bufB, N);

        // attention pooling
        colsum_kernel<<<256, TPB, 0, stream>>>(bufB, N, colsum);
        cvec_kernel<<<1, 64, 0, stream>>>(colsum, Wa, 1.0f / (float)N, cvec);
        pool_kernel<<<256, TPB, 0, stream>>>(bufB, N, cvec, reps[g]);
    }

    final_kernel<<<1, 64, 0, stream>>>(rep1, rep2, Wt, Wb, bt, Wfc, bfc, Wsc, bsc, out);
}

// Round 3
// 569.342 us; speedup vs baseline: 1.7356x; 1.4394x over previous
//
#include <hip/hip_runtime.h>
#include <hip/hip_bf16.h>

#define TPB 256

// ---------------- CSR build ----------------

__global__ void count_kernel(const int* __restrict__ dst, int E, int* __restrict__ cnt) {
    int e = blockIdx.x * blockDim.x + threadIdx.x;
    if (e < E) atomicAdd(&cnt[dst[e]], 1);
}

// Phase 1: per-block (1024-element chunk) local exclusive scan + block totals.
// Also computes dinv[i] = rsqrt(cnt[i]+1) since cnt is already in registers.
__global__ void scan1_kernel(const int* __restrict__ cnt, int n,
                             int* __restrict__ off, int* __restrict__ bsum,
                             float* __restrict__ dinv) {
    __shared__ int tsum[TPB];
    int base = blockIdx.x * 1024;
    int i0 = base + (int)threadIdx.x * 4;
    int vals[4];
    int s = 0;
#pragma unroll
    for (int k = 0; k < 4; k++) {
        int i = i0 + k;
        vals[k] = (i < n) ? cnt[i] : 0;
        s += vals[k];
    }
    tsum[threadIdx.x] = s;
    __syncthreads();
    for (int st = 1; st < TPB; st <<= 1) {
        int t = (threadIdx.x >= (unsigned)st) ? tsum[threadIdx.x - st] : 0;
        __syncthreads();
        tsum[threadIdx.x] += t;
        __syncthreads();
    }
    int running = tsum[threadIdx.x] - s;  // exclusive base for this thread
#pragma unroll
    for (int k = 0; k < 4; k++) {
        int i = i0 + k;
        if (i < n) {
            off[i] = running;
            dinv[i] = rsqrtf((float)vals[k] + 1.0f);
        }
        running += vals[k];
    }
    if (threadIdx.x == TPB - 1) bsum[blockIdx.x] = tsum[TPB - 1];
}

// Phase 2: one wave exclusive-scans the block totals (nb <= 64), writes grand total.
__global__ void scan2_kernel(int* __restrict__ bsum, int nb, int* __restrict__ offN) {
    int t = threadIdx.x;  // 64 threads
    int orig = (t < nb) ? bsum[t] : 0;
    int v = orig;
    for (int d = 1; d < 64; d <<= 1) {
        int u = __shfl_up(v, d, 64);
        if (t >= d) v += u;
    }
    int total = __shfl(v, 63, 64);
    if (t < nb) bsum[t] = v - orig;  // exclusive
    if (t == 0) offN[0] = total;
}

// Phase 3: add block bases; produce final off and cur.
__global__ void scan3_kernel(int* __restrict__ off, int* __restrict__ cur,
                             const int* __restrict__ bsum, int n) {
    int i = blockIdx.x * blockDim.x + threadIdx.x;
    if (i < n) {
        int v = off[i] + bsum[i >> 10];
        off[i] = v;
        cur[i] = v;
    }
}

__global__ void fill_kernel(const int* __restrict__ src, const int* __restrict__ dst, int E,
                            int* __restrict__ cur, int* __restrict__ col) {
    int e = blockIdx.x * blockDim.x + threadIdx.x;
    if (e < E) {
        int p = atomicAdd(&cur[dst[e]], 1);
        col[p] = src[e];
    }
}

// ---------------- dense matmul: Y[n,COUT] = dinv[n] * (X[n,CIN] @ W[CIN,COUT]) ----------
// Register-tiled: block = 256 threads; thread computes TM nodes x 4 channels.
// Epilogue fuses the dinv_j scaling so the aggregation gather needs only one load/edge.

template <int CIN, int COUT, int TM>
__global__ void matmul_kernel(const float* __restrict__ X, const float* __restrict__ W,
                              const float* __restrict__ dinv, float* __restrict__ Y, int n) {
    constexpr int G = COUT / 4;    // channel groups (float4 each)
    constexpr int S = 256 / G;     // node slots
    constexpr int BN = S * TM;     // nodes per block
    constexpr int XS = CIN + 1;    // padded row stride (kills slot-stride bank conflicts)
    constexpr int CH = CIN / 4;    // float4 chunks per X row
    __shared__ float Xs[BN * XS];
    __shared__ float Ws[CIN * COUT];

    // stage W (contiguous float4)
    for (int i = threadIdx.x; i < CIN * COUT / 4; i += 256)
        ((float4*)Ws)[i] = ((const float4*)W)[i];
    // stage X tile (coalesced float4 reads along k; padded scalar LDS writes)
    int n0 = blockIdx.x * BN;
    for (int i = threadIdx.x; i < BN * CH; i += 256) {
        int nn = i / CH, kc = i % CH;
        float4 v = make_float4(0.f, 0.f, 0.f, 0.f);
        if (n0 + nn < n) v = *(const float4*)&X[(size_t)(n0 + nn) * CIN + 4 * kc];
        float* d = &Xs[nn * XS + 4 * kc];
        d[0] = v.x; d[1] = v.y; d[2] = v.z; d[3] = v.w;
    }
    __syncthreads();

    int cg = threadIdx.x % G;
    int slot = threadIdx.x / G;
    int c0 = cg * 4;
    float4 acc[TM];
#pragma unroll
    for (int i = 0; i < TM; i++) acc[i] = make_float4(0.f, 0.f, 0.f, 0.f);

    for (int k = 0; k < CIN; k++) {
        float4 b = *(const float4*)&Ws[k * COUT + c0];
#pragma unroll
        for (int i = 0; i < TM; i++) {
            float a = Xs[(slot * TM + i) * XS + k];
            acc[i].x += a * b.x;
            acc[i].y += a * b.y;
            acc[i].z += a * b.z;
            acc[i].w += a * b.w;
        }
    }
#pragma unroll
    for (int i = 0; i < TM; i++) {
        int node = n0 + slot * TM + i;
        if (node < n) {
            float d = dinv[node];
            float4 r = make_float4(acc[i].x * d, acc[i].y * d, acc[i].z * d, acc[i].w * d);
            *(float4*)&Y[(size_t)node * COUT + c0] = r;
        }
    }
}

// ---------------- GCN aggregation (gather over CSR-by-dst) ----------------
// HW is pre-scaled by dinv_j. out[i,c] = act(dinv_i*(sum_j HW[j,c] + HW[i,c]) + b[c])

template <int C, bool RELU>
__global__ void agg_kernel(const float* __restrict__ HW, const int* __restrict__ off,
                           const int* __restrict__ col, const float* __restrict__ dinv,
                           const float* __restrict__ bias, float* __restrict__ out, int n) {
    constexpr int CH = C / 4;
    int tid = blockIdx.x * blockDim.x + threadIdx.x;
    int node = tid / CH;
    if (node >= n) return;
    int c0 = (tid % CH) * 4;
    int s = off[node], e = off[node + 1];
    float4 a0 = make_float4(0.f, 0.f, 0.f, 0.f);
    float4 a1 = make_float4(0.f, 0.f, 0.f, 0.f);
    int p = s;
    for (; p + 2 <= e; p += 2) {
        int j0 = col[p];
        int j1 = col[p + 1];
        float4 v0 = *(const float4*)&HW[(size_t)j0 * C + c0];
        float4 v1 = *(const float4*)&HW[(size_t)j1 * C + c0];
        a0.x += v0.x; a0.y += v0.y; a0.z += v0.z; a0.w += v0.w;
        a1.x += v1.x; a1.y += v1.y; a1.z += v1.z; a1.w += v1.w;
    }
    if (p < e) {
        int j = col[p];
        float4 v = *(const float4*)&HW[(size_t)j * C + c0];
        a0.x += v.x; a0.y += v.y; a0.z += v.z; a0.w += v.w;
    }
    float4 self = *(const float4*)&HW[(size_t)node * C + c0];
    float di = dinv[node];
    float4 b4 = *(const float4*)&bias[c0];
    float4 r;
    r.x = di * (a0.x + a1.x + self.x) + b4.x;
    r.y = di * (a0.y + a1.y + self.y) + b4.y;
    r.z = di * (a0.z + a1.z + self.z) + b4.z;
    r.w = di * (a0.w + a1.w + self.w) + b4.w;
    if (RELU) {
        r.x = fmaxf(r.x, 0.f); r.y = fmaxf(r.y, 0.f);
        r.z = fmaxf(r.z, 0.f); r.w = fmaxf(r.w, 0.f);
    }
    *(float4*)&out[(size_t)node * C + c0] = r;
}

// ---------------- attention pooling ----------------

__global__ void colsum_kernel(const float* __restrict__ H, int n, float* __restrict__ colsum) {
    int c = threadIdx.x % 16;
    int w = (blockIdx.x * blockDim.x + threadIdx.x) / 16;
    int stride = (gridDim.x * blockDim.x) / 16;
    float acc = 0.f;
    for (int node = w; node < n; node += stride) acc += H[(size_t)node * 16 + c];
    __shared__ float sdata[TPB];
    sdata[threadIdx.x] = acc;
    __syncthreads();
    if (threadIdx.x < 16) {
        float s = 0.f;
        for (int t = threadIdx.x; t < TPB; t += 16) s += sdata[t];
        atomicAdd(&colsum[threadIdx.x], s);
    }
}

__global__ void cvec_kernel(const float* __restrict__ colsum, const float* __restrict__ Wa,
                            float n_inv, float* __restrict__ cvec) {
    int j = threadIdx.x;
    if (j < 16) {
        float acc = 0.f;
        for (int i = 0; i < 16; i++) acc += (colsum[i] * n_inv) * Wa[i * 16 + j];
        cvec[j] = tanhf(acc);
    }
}

__global__ void pool_kernel(const float* __restrict__ H, int n, const float* __restrict__ cvec,
                            float* __restrict__ rep) {
    int c = threadIdx.x % 16;
    float cv = cvec[c];
    int w = (blockIdx.x * blockDim.x + threadIdx.x) / 16;
    int stride = (gridDim.x * blockDim.x) / 16;
    float acc = 0.f;
    for (int node = w; node < n; node += stride) {
        float x = H[(size_t)node * 16 + c];
        float p = x * cv;
        p += __shfl_xor(p, 1, 16);
        p += __shfl_xor(p, 2, 16);
        p += __shfl_xor(p, 4, 16);
        p += __shfl_xor(p, 8, 16);
        float s = 1.f / (1.f + __expf(-p));
        acc += s * x;
    }
    __shared__ float sdata[TPB];
    sdata[threadIdx.x] = acc;
    __syncthreads();
    if (threadIdx.x < 16) {
        float s = 0.f;
        for (int t = threadIdx.x; t < TPB; t += 16) s += sdata[t];
        atomicAdd(&rep[threadIdx.x], s);
    }
}

// ---------------- final tensor-network scoring ----------------

__global__ void final_kernel(const float* __restrict__ e1, const float* __restrict__ e2,
                             const float* __restrict__ Wt, const float* __restrict__ Wb,
                             const float* __restrict__ bt, const float* __restrict__ Wfc,
                             const float* __restrict__ bfc, const float* __restrict__ Wsc,
                             const float* __restrict__ bsc, float* __restrict__ out) {
    __shared__ float scores[16], tvec[16], se1[16], se2[16];
    int t = threadIdx.x;
    if (t < 16) { se1[t] = e1[t]; se2[t] = e2[t]; }
    __syncthreads();
    if (t < 16) {
        float bil = 0.f;
        for (int i = 0; i < 16; i++) {
            float a = se1[i];
            for (int j = 0; j < 16; j++) bil += a * se2[j] * Wt[(i * 16 + j) * 16 + t];
        }
        float blk = 0.f;
        for (int m = 0; m < 16; m++)
            blk += Wb[t * 32 + m] * se1[m] + Wb[t * 32 + 16 + m] * se2[m];
        scores[t] = fmaxf(bil + blk + bt[t], 0.f);
    }
    __syncthreads();
    if (t < 16) {
        float acc = bfc[t];
        for (int k = 0; k < 16; k++) acc += scores[k] * Wfc[k * 16 + t];
        tvec[t] = tanhf(acc);
    }
    __syncthreads();
    if (t == 0) {
        float acc = bsc[0];
        for (int j = 0; j < 16; j++) acc += tvec[j] * Wsc[j];
        out[0] = 1.f / (1.f + __expf(-acc));
    }
}

// ---------------- launcher ----------------

extern "C" void kernel_launch(void* const* d_in, const int* in_sizes, int n_in,
                              void* d_out, int out_size, void* d_ws, size_t ws_size,
                              hipStream_t stream) {
    const float* X1 = (const float*)d_in[0];
    const float* X2 = (const float*)d_in[1];
    const int* edges1 = (const int*)d_in[2];
    const int* edges2 = (const int*)d_in[3];
    const float* W1 = (const float*)d_in[4];
    const float* b1 = (const float*)d_in[5];
    const float* W2 = (const float*)d_in[6];
    const float* b2 = (const float*)d_in[7];
    const float* W3 = (const float*)d_in[8];
    const float* b3 = (const float*)d_in[9];
    const float* Wa = (const float*)d_in[10];
    const float* Wt = (const float*)d_in[11];
    const float* Wb = (const float*)d_in[12];
    const float* bt = (const float*)d_in[13];
    const float* Wfc = (const float*)d_in[14];
    const float* bfc = (const float*)d_in[15];
    const float* Wsc = (const float*)d_in[16];
    const float* bsc = (const float*)d_in[17];
    float* out = (float*)d_out;

    const int N = in_sizes[0] / 96;
    const int E = in_sizes[2] / 2;
    const int NB = (N + 1023) / 1024;  // scan chunks (49 for N=50000; must be <= 64)

    // workspace layout (256B aligned chunks)
    char* ws = (char*)d_ws;
    size_t o = 0;
    auto alloc = [&](size_t bytes) {
        void* p = ws + o;
        o += (bytes + 255) & ~(size_t)255;
        return p;
    };
    int* cnt = (int*)alloc((size_t)N * 4);
    int* off = (int*)alloc((size_t)(N + 1) * 4);
    int* cur = (int*)alloc((size_t)N * 4);
    int* col = (int*)alloc((size_t)E * 4);
    int* bsum = (int*)alloc((size_t)64 * 4);
    float* dinv = (float*)alloc((size_t)N * 4);
    float* small = (float*)alloc(96 * 4);  // colsum(16) cvec(16) rep1(16) rep2(16)
    float* colsum = small;
    float* cvec = small + 16;
    float* rep1 = small + 32;
    float* rep2 = small + 48;
    float* bufA = (float*)alloc((size_t)N * 64 * 4);
    float* bufB = (float*)alloc((size_t)N * 64 * 4);

    const int gE = (E + TPB - 1) / TPB;
    const int gN = (N + TPB - 1) / TPB;

    hipMemsetAsync(small, 0, 96 * 4, stream);

    const float* Xs[2] = {X1, X2};
    const int* Es[2] = {edges1, edges2};
    float* reps[2] = {rep1, rep2};

    for (int g = 0; g < 2; g++) {
        const int* src = Es[g];
        const int* dst = Es[g] + E;

        hipMemsetAsync(cnt, 0, (size_t)N * 4, stream);
        if (g == 1) hipMemsetAsync(colsum, 0, 16 * 4, stream);

        count_kernel<<<gE, TPB, 0, stream>>>(dst, E, cnt);
        scan1_kernel<<<NB, TPB, 0, stream>>>(cnt, N, off, bsum, dinv);
        scan2_kernel<<<1, 64, 0, stream>>>(bsum, NB, off + N);
        scan3_kernel<<<gN, TPB, 0, stream>>>(off, cur, bsum, N);
        fill_kernel<<<gE, TPB, 0, stream>>>(src, dst, E, cur, col);

        // layer 1: 96 -> 64 (BN=128 nodes/block), agg + relu
        matmul_kernel<96, 64, 8><<<(N + 127) / 128, TPB, 0, stream>>>(Xs[g], W1, dinv, bufA, N);
        agg_kernel<64, true><<<((size_t)N * 16 + TPB - 1) / TPB, TPB, 0, stream>>>(bufA, off, col, dinv, b1, bufB, N);
        // layer 2: 64 -> 32, agg + relu
        matmul_kernel<64, 32, 4><<<(N + 127) / 128, TPB, 0, stream>>>(bufB, W2, dinv, bufA, N);
        agg_kernel<32, true><<<((size_t)N * 8 + TPB - 1) / TPB, TPB, 0, stream>>>(bufA, off, col, dinv, b2, bufB, N);
        // layer 3: 32 -> 16, agg, no relu
        matmul_kernel<32, 16, 2><<<(N + 127) / 128, TPB, 0, stream>>>(bufB, W3, dinv, bufA, N);
        agg_kernel<16, false><<<((size_t)N * 4 + TPB - 1) / TPB, TPB, 0, stream>>>(bufA, off, col, dinv, b3, bufB, N);

        // attention pooling
        colsum_kernel<<<256, TPB, 0, stream>>>(bufB, N, colsum);
        cvec_kernel<<<1, 64, 0, stream>>>(colsum, Wa, 1.0f / (float)N, cvec);
        pool_kernel<<<256, TPB, 0, stream>>>(bufB, N, cvec, reps[g]);
    }

    final_kernel<<<1, 64, 0, stream>>>(rep1, rep2, Wt, Wb, bt, Wfc, bfc, Wsc, bsc, out);
}

// Round 4
// 478.338 us; speedup vs baseline: 2.0658x; 1.1902x over previous
//
#include <hip/hip_runtime.h>
#include <hip/hip_bf16.h>

#define TPB 256
#define SH 6
#define BW 64  // nodes per bucket = 1<<SH; NBUK must be <= 1024 (N <= 65536)

// ---------------- bucketed CSR build ----------------

// Per-block LDS histogram of dst buckets -> few global atomics.
__global__ void bucket_count_kernel(const int* __restrict__ dst, int E,
                                    int* __restrict__ bcnt, int nbuk) {
    __shared__ int hist[1024];
    for (int t = threadIdx.x; t < 1024; t += TPB) hist[t] = 0;
    __syncthreads();
    int base = blockIdx.x * 8192;
    int end = min(base + 8192, E);
    for (int e = base + (int)threadIdx.x; e < end; e += TPB)
        atomicAdd(&hist[dst[e] >> SH], 1);
    __syncthreads();
    for (int t = threadIdx.x; t < nbuk; t += TPB) {
        int h = hist[t];
        if (h) atomicAdd(&bcnt[t], h);
    }
}

// Single-block exclusive scan of bucket counts (nbuk <= 1024).
__global__ void bucket_scan_kernel(const int* __restrict__ bcnt, int nbuk,
                                   int* __restrict__ boff, int* __restrict__ bcur) {
    __shared__ int s[1024];
    int t = threadIdx.x;
    int v = (t < nbuk) ? bcnt[t] : 0;
    s[t] = v;
    __syncthreads();
    for (int st = 1; st < 1024; st <<= 1) {
        int u = (t >= st) ? s[t - st] : 0;
        __syncthreads();
        s[t] += u;
        __syncthreads();
    }
    if (t < nbuk) { int e = s[t] - v; boff[t] = e; bcur[t] = e; }
}

// Bin edges into bucket-contiguous regions of ebuf, packed (src<<SH)|(dst&63).
// Each block reserves one run per bucket (LDS rank + one global atomic per bucket).
__global__ void bucket_scatter_kernel(const int* __restrict__ src, const int* __restrict__ dst,
                                      int E, int* __restrict__ bcur, int* __restrict__ ebuf,
                                      int nbuk) {
    __shared__ int hist[1024];
    for (int t = threadIdx.x; t < 1024; t += TPB) hist[t] = 0;
    __syncthreads();
    int base = blockIdx.x * 4096;
    int pk[16], bk[16], rk[16];
#pragma unroll
    for (int k = 0; k < 16; k++) {
        int e = base + k * TPB + (int)threadIdx.x;
        bk[k] = -1;
        if (e < E) {
            int s = src[e], d = dst[e];
            int b = d >> SH;
            bk[k] = b;
            pk[k] = (s << SH) | (d & (BW - 1));
            rk[k] = atomicAdd(&hist[b], 1);
        }
    }
    __syncthreads();
    for (int t = threadIdx.x; t < nbuk; t += TPB) {
        int h = hist[t];
        hist[t] = h ? atomicAdd(&bcur[t], h) : 0;
    }
    __syncthreads();
#pragma unroll
    for (int k = 0; k < 16; k++)
        if (bk[k] >= 0) ebuf[hist[bk[k]] + rk[k]] = pk[k];
}

// Per-bucket node in-degree histogram -> cnt (no global atomics).
__global__ void bucket_cnt_kernel(const int* __restrict__ ebuf, const int* __restrict__ boff,
                                  const int* __restrict__ bcnt, int n, int* __restrict__ cnt) {
    __shared__ int h[BW];
    int b = blockIdx.x;
    if (threadIdx.x < BW) h[threadIdx.x] = 0;
    __syncthreads();
    int s = boff[b], e = s + bcnt[b];
    for (int i = s + (int)threadIdx.x; i < e; i += TPB)
        atomicAdd(&h[ebuf[i] & (BW - 1)], 1);
    __syncthreads();
    int node = b * BW + (int)threadIdx.x;
    if (threadIdx.x < BW && node < n) cnt[node] = h[threadIdx.x];
}

// Per-bucket fill of col: writes land in one contiguous ~4KB slice per block.
__global__ void bucket_fill_kernel(const int* __restrict__ ebuf, const int* __restrict__ boff,
                                   const int* __restrict__ bcnt, const int* __restrict__ off,
                                   int n, int* __restrict__ col) {
    __shared__ int nbase[BW];
    __shared__ int nrank[BW];
    int b = blockIdx.x;
    if (threadIdx.x < BW) {
        int node = b * BW + (int)threadIdx.x;
        nbase[threadIdx.x] = (node < n) ? off[node] : 0;
        nrank[threadIdx.x] = 0;
    }
    __syncthreads();
    int s = boff[b], e = s + bcnt[b];
    for (int i = s + (int)threadIdx.x; i < e; i += TPB) {
        int p = ebuf[i];
        int lo = p & (BW - 1);
        int r = atomicAdd(&nrank[lo], 1);
        col[nbase[lo] + r] = p >> SH;
    }
}

// ---------------- node-level offset scan ----------------

// Phase 1: per-block (1024-element chunk) local exclusive scan + block totals.
// Also computes dinv[i] = rsqrt(cnt[i]+1) since cnt is already in registers.
__global__ void scan1_kernel(const int* __restrict__ cnt, int n,
                             int* __restrict__ off, int* __restrict__ bsum,
                             float* __restrict__ dinv) {
    __shared__ int tsum[TPB];
    int base = blockIdx.x * 1024;
    int i0 = base + (int)threadIdx.x * 4;
    int vals[4];
    int s = 0;
#pragma unroll
    for (int k = 0; k < 4; k++) {
        int i = i0 + k;
        vals[k] = (i < n) ? cnt[i] : 0;
        s += vals[k];
    }
    tsum[threadIdx.x] = s;
    __syncthreads();
    for (int st = 1; st < TPB; st <<= 1) {
        int t = (threadIdx.x >= (unsigned)st) ? tsum[threadIdx.x - st] : 0;
        __syncthreads();
        tsum[threadIdx.x] += t;
        __syncthreads();
    }
    int running = tsum[threadIdx.x] - s;  // exclusive base for this thread
#pragma unroll
    for (int k = 0; k < 4; k++) {
        int i = i0 + k;
        if (i < n) {
            off[i] = running;
            dinv[i] = rsqrtf((float)vals[k] + 1.0f);
        }
        running += vals[k];
    }
    if (threadIdx.x == TPB - 1) bsum[blockIdx.x] = tsum[TPB - 1];
}

// Phase 2: one wave exclusive-scans the block totals (nb <= 64), writes grand total.
__global__ void scan2_kernel(int* __restrict__ bsum, int nb, int* __restrict__ offN) {
    int t = threadIdx.x;  // 64 threads
    int orig = (t < nb) ? bsum[t] : 0;
    int v = orig;
    for (int d = 1; d < 64; d <<= 1) {
        int u = __shfl_up(v, d, 64);
        if (t >= d) v += u;
    }
    int total = __shfl(v, 63, 64);
    if (t < nb) bsum[t] = v - orig;  // exclusive
    if (t == 0) offN[0] = total;
}

// Phase 3: add block bases.
__global__ void scan3_kernel(int* __restrict__ off, const int* __restrict__ bsum, int n) {
    int i = blockIdx.x * blockDim.x + threadIdx.x;
    if (i < n) off[i] += bsum[i >> 10];
}

// ---------------- dense matmul: Y[n,COUT] = dinv[n] * (X[n,CIN] @ W[CIN,COUT]) ----------
// Register-tiled: block = 256 threads; thread computes TM nodes x 4 channels.
// Epilogue fuses the dinv_j scaling so the aggregation gather needs only one load/edge.

template <int CIN, int COUT, int TM>
__global__ void matmul_kernel(const float* __restrict__ X, const float* __restrict__ W,
                              const float* __restrict__ dinv, float* __restrict__ Y, int n) {
    constexpr int G = COUT / 4;    // channel groups (float4 each)
    constexpr int S = 256 / G;     // node slots
    constexpr int BN = S * TM;     // nodes per block
    constexpr int XS = CIN + 1;    // padded row stride (kills slot-stride bank conflicts)
    constexpr int CH = CIN / 4;    // float4 chunks per X row
    __shared__ float Xs[BN * XS];
    __shared__ float Ws[CIN * COUT];

    // stage W (contiguous float4)
    for (int i = threadIdx.x; i < CIN * COUT / 4; i += 256)
        ((float4*)Ws)[i] = ((const float4*)W)[i];
    // stage X tile (coalesced float4 reads along k; padded scalar LDS writes)
    int n0 = blockIdx.x * BN;
    for (int i = threadIdx.x; i < BN * CH; i += 256) {
        int nn = i / CH, kc = i % CH;
        float4 v = make_float4(0.f, 0.f, 0.f, 0.f);
        if (n0 + nn < n) v = *(const float4*)&X[(size_t)(n0 + nn) * CIN + 4 * kc];
        float* d = &Xs[nn * XS + 4 * kc];
        d[0] = v.x; d[1] = v.y; d[2] = v.z; d[3] = v.w;
    }
    __syncthreads();

    int cg = threadIdx.x % G;
    int slot = threadIdx.x / G;
    int c0 = cg * 4;
    float4 acc[TM];
#pragma unroll
    for (int i = 0; i < TM; i++) acc[i] = make_float4(0.f, 0.f, 0.f, 0.f);

    for (int k = 0; k < CIN; k++) {
        float4 b = *(const float4*)&Ws[k * COUT + c0];
#pragma unroll
        for (int i = 0; i < TM; i++) {
            float a = Xs[(slot * TM + i) * XS + k];
            acc[i].x += a * b.x;
            acc[i].y += a * b.y;
            acc[i].z += a * b.z;
            acc[i].w += a * b.w;
        }
    }
#pragma unroll
    for (int i = 0; i < TM; i++) {
        int node = n0 + slot * TM + i;
        if (node < n) {
            float d = dinv[node];
            float4 r = make_float4(acc[i].x * d, acc[i].y * d, acc[i].z * d, acc[i].w * d);
            *(float4*)&Y[(size_t)node * COUT + c0] = r;
        }
    }
}

// ---------------- GCN aggregation (gather over CSR-by-dst) ----------------
// HW is pre-scaled by dinv_j. out[i,c] = act(dinv_i*(sum_j HW[j,c] + HW[i,c]) + b[c])

template <int C, bool RELU>
__global__ void agg_kernel(const float* __restrict__ HW, const int* __restrict__ off,
                           const int* __restrict__ col, const float* __restrict__ dinv,
                           const float* __restrict__ bias, float* __restrict__ out, int n) {
    constexpr int CH = C / 4;
    int tid = blockIdx.x * blockDim.x + threadIdx.x;
    int node = tid / CH;
    if (node >= n) return;
    int c0 = (tid % CH) * 4;
    int s = off[node], e = off[node + 1];
    float4 a0 = make_float4(0.f, 0.f, 0.f, 0.f);
    float4 a1 = make_float4(0.f, 0.f, 0.f, 0.f);
    int p = s;
    for (; p + 2 <= e; p += 2) {
        int j0 = col[p];
        int j1 = col[p + 1];
        float4 v0 = *(const float4*)&HW[(size_t)j0 * C + c0];
        float4 v1 = *(const float4*)&HW[(size_t)j1 * C + c0];
        a0.x += v0.x; a0.y += v0.y; a0.z += v0.z; a0.w += v0.w;
        a1.x += v1.x; a1.y += v1.y; a1.z += v1.z; a1.w += v1.w;
    }
    if (p < e) {
        int j = col[p];
        float4 v = *(const float4*)&HW[(size_t)j * C + c0];
        a0.x += v.x; a0.y += v.y; a0.z += v.z; a0.w += v.w;
    }
    float4 self = *(const float4*)&HW[(size_t)node * C + c0];
    float di = dinv[node];
    float4 b4 = *(const float4*)&bias[c0];
    float4 r;
    r.x = di * (a0.x + a1.x + self.x) + b4.x;
    r.y = di * (a0.y + a1.y + self.y) + b4.y;
    r.z = di * (a0.z + a1.z + self.z) + b4.z;
    r.w = di * (a0.w + a1.w + self.w) + b4.w;
    if (RELU) {
        r.x = fmaxf(r.x, 0.f); r.y = fmaxf(r.y, 0.f);
        r.z = fmaxf(r.z, 0.f); r.w = fmaxf(r.w, 0.f);
    }
    *(float4*)&out[(size_t)node * C + c0] = r;
}

// ---------------- attention pooling ----------------

__global__ void colsum_kernel(const float* __restrict__ H, int n, float* __restrict__ colsum) {
    int c = threadIdx.x % 16;
    int w = (blockIdx.x * blockDim.x + threadIdx.x) / 16;
    int stride = (gridDim.x * blockDim.x) / 16;
    float acc = 0.f;
    for (int node = w; node < n; node += stride) acc += H[(size_t)node * 16 + c];
    __shared__ float sdata[TPB];
    sdata[threadIdx.x] = acc;
    __syncthreads();
    if (threadIdx.x < 16) {
        float s = 0.f;
        for (int t = threadIdx.x; t < TPB; t += 16) s += sdata[t];
        atomicAdd(&colsum[threadIdx.x], s);
    }
}

__global__ void cvec_kernel(const float* __restrict__ colsum, const float* __restrict__ Wa,
                            float n_inv, float* __restrict__ cvec) {
    int j = threadIdx.x;
    if (j < 16) {
        float acc = 0.f;
        for (int i = 0; i < 16; i++) acc += (colsum[i] * n_inv) * Wa[i * 16 + j];
        cvec[j] = tanhf(acc);
    }
}

__global__ void pool_kernel(const float* __restrict__ H, int n, const float* __restrict__ cvec,
                            float* __restrict__ rep) {
    int c = threadIdx.x % 16;
    float cv = cvec[c];
    int w = (blockIdx.x * blockDim.x + threadIdx.x) / 16;
    int stride = (gridDim.x * blockDim.x) / 16;
    float acc = 0.f;
    for (int node = w; node < n; node += stride) {
        float x = H[(size_t)node * 16 + c];
        float p = x * cv;
        p += __shfl_xor(p, 1, 16);
        p += __shfl_xor(p, 2, 16);
        p += __shfl_xor(p, 4, 16);
        p += __shfl_xor(p, 8, 16);
        float s = 1.f / (1.f + __expf(-p));
        acc += s * x;
    }
    __shared__ float sdata[TPB];
    sdata[threadIdx.x] = acc;
    __syncthreads();
    if (threadIdx.x < 16) {
        float s = 0.f;
        for (int t = threadIdx.x; t < TPB; t += 16) s += sdata[t];
        atomicAdd(&rep[threadIdx.x], s);
    }
}

// ---------------- final tensor-network scoring ----------------

__global__ void final_kernel(const float* __restrict__ e1, const float* __restrict__ e2,
                             const float* __restrict__ Wt, const float* __restrict__ Wb,
                             const float* __restrict__ bt, const float* __restrict__ Wfc,
                             const float* __restrict__ bfc, const float* __restrict__ Wsc,
                             const float* __restrict__ bsc, float* __restrict__ out) {
    __shared__ float scores[16], tvec[16], se1[16], se2[16];
    int t = threadIdx.x;
    if (t < 16) { se1[t] = e1[t]; se2[t] = e2[t]; }
    __syncthreads();
    if (t < 16) {
        float bil = 0.f;
        for (int i = 0; i < 16; i++) {
            float a = se1[i];
            for (int j = 0; j < 16; j++) bil += a * se2[j] * Wt[(i * 16 + j) * 16 + t];
        }
        float blk = 0.f;
        for (int m = 0; m < 16; m++)
            blk += Wb[t * 32 + m] * se1[m] + Wb[t * 32 + 16 + m] * se2[m];
        scores[t] = fmaxf(bil + blk + bt[t], 0.f);
    }
    __syncthreads();
    if (t < 16) {
        float acc = bfc[t];
        for (int k = 0; k < 16; k++) acc += scores[k] * Wfc[k * 16 + t];
        tvec[t] = tanhf(acc);
    }
    __syncthreads();
    if (t == 0) {
        float acc = bsc[0];
        for (int j = 0; j < 16; j++) acc += tvec[j] * Wsc[j];
        out[0] = 1.f / (1.f + __expf(-acc));
    }
}

// ---------------- launcher ----------------

extern "C" void kernel_launch(void* const* d_in, const int* in_sizes, int n_in,
                              void* d_out, int out_size, void* d_ws, size_t ws_size,
                              hipStream_t stream) {
    const float* X1 = (const float*)d_in[0];
    const float* X2 = (const float*)d_in[1];
    const int* edges1 = (const int*)d_in[2];
    const int* edges2 = (const int*)d_in[3];
    const float* W1 = (const float*)d_in[4];
    const float* b1 = (const float*)d_in[5];
    const float* W2 = (const float*)d_in[6];
    const float* b2 = (const float*)d_in[7];
    const float* W3 = (const float*)d_in[8];
    const float* b3 = (const float*)d_in[9];
    const float* Wa = (const float*)d_in[10];
    const float* Wt = (const float*)d_in[11];
    const float* Wb = (const float*)d_in[12];
    const float* bt = (const float*)d_in[13];
    const float* Wfc = (const float*)d_in[14];
    const float* bfc = (const float*)d_in[15];
    const float* Wsc = (const float*)d_in[16];
    const float* bsc = (const float*)d_in[17];
    float* out = (float*)d_out;

    const int N = in_sizes[0] / 96;
    const int E = in_sizes[2] / 2;
    const int NB = (N + 1023) / 1024;   // node-scan chunks (must be <= 64)
    const int NBUK = (N + BW - 1) / BW; // buckets (must be <= 1024)

    // workspace layout (256B aligned chunks)
    char* ws = (char*)d_ws;
    size_t o = 0;
    auto alloc = [&](size_t bytes) {
        void* p = ws + o;
        o += (bytes + 255) & ~(size_t)255;
        return p;
    };
    int* cnt = (int*)alloc((size_t)N * 4);
    int* off = (int*)alloc((size_t)(N + 1) * 4);
    int* col = (int*)alloc((size_t)E * 4);
    int* bsum = (int*)alloc((size_t)64 * 4);
    int* bcnt = (int*)alloc((size_t)1024 * 4);
    int* boff = (int*)alloc((size_t)1024 * 4);
    int* bcur = (int*)alloc((size_t)1024 * 4);
    float* dinv = (float*)alloc((size_t)N * 4);
    float* small = (float*)alloc(96 * 4);  // colsum(16) cvec(16) rep1(16) rep2(16)
    float* colsum = small;
    float* cvec = small + 16;
    float* rep1 = small + 32;
    float* rep2 = small + 48;
    float* bufA = (float*)alloc((size_t)N * 64 * 4);
    float* bufB = (float*)alloc((size_t)N * 64 * 4);
    int* ebuf = (int*)bufA;  // ebuf (E ints) is dead before matmul first writes bufA

    const int gN = (N + TPB - 1) / TPB;
    const int gB1 = (E + 8191) / 8192;
    const int gB2 = (E + 4095) / 4096;

    hipMemsetAsync(small, 0, 96 * 4, stream);

    const float* Xs[2] = {X1, X2};
    const int* Es[2] = {edges1, edges2};
    float* reps[2] = {rep1, rep2};

    for (int g = 0; g < 2; g++) {
        const int* src = Es[g];
        const int* dst = Es[g] + E;

        hipMemsetAsync(bcnt, 0, (size_t)NBUK * 4, stream);
        if (g == 1) hipMemsetAsync(colsum, 0, 16 * 4, stream);

        // bucketed CSR build
        bucket_count_kernel<<<gB1, TPB, 0, stream>>>(dst, E, bcnt, NBUK);
        bucket_scan_kernel<<<1, 1024, 0, stream>>>(bcnt, NBUK, boff, bcur);
        bucket_scatter_kernel<<<gB2, TPB, 0, stream>>>(src, dst, E, bcur, ebuf, NBUK);
        bucket_cnt_kernel<<<NBUK, TPB, 0, stream>>>(ebuf, boff, bcnt, N, cnt);
        scan1_kernel<<<NB, TPB, 0, stream>>>(cnt, N, off, bsum, dinv);
        scan2_kernel<<<1, 64, 0, stream>>>(bsum, NB, off + N);
        scan3_kernel<<<gN, TPB, 0, stream>>>(off, bsum, N);
        bucket_fill_kernel<<<NBUK, TPB, 0, stream>>>(ebuf, boff, bcnt, off, N, col);

        // layer 1: 96 -> 64 (BN=128 nodes/block), agg + relu
        matmul_kernel<96, 64, 8><<<(N + 127) / 128, TPB, 0, stream>>>(Xs[g], W1, dinv, bufA, N);
        agg_kernel<64, true><<<((size_t)N * 16 + TPB - 1) / TPB, TPB, 0, stream>>>(bufA, off, col, dinv, b1, bufB, N);
        // layer 2: 64 -> 32, agg + relu
        matmul_kernel<64, 32, 4><<<(N + 127) / 128, TPB, 0, stream>>>(bufB, W2, dinv, bufA, N);
        agg_kernel<32, true><<<((size_t)N * 8 + TPB - 1) / TPB, TPB, 0, stream>>>(bufA, off, col, dinv, b2, bufB, N);
        // layer 3: 32 -> 16, agg, no relu
        matmul_kernel<32, 16, 2><<<(N + 127) / 128, TPB, 0, stream>>>(bufB, W3, dinv, bufA, N);
        agg_kernel<16, false><<<((size_t)N * 4 + TPB - 1) / TPB, TPB, 0, stream>>>(bufA, off, col, dinv, b3, bufB, N);

        // attention pooling
        colsum_kernel<<<256, TPB, 0, stream>>>(bufB, N, colsum);
        cvec_kernel<<<1, 64, 0, stream>>>(colsum, Wa, 1.0f / (float)N, cvec);
        pool_kernel<<<256, TPB, 0, stream>>>(bufB, N, cvec, reps[g]);
    }

    final_kernel<<<1, 64, 0, stream>>>(rep1, rep2, Wt, Wb, bt, Wfc, bfc, Wsc, bsc, out);
}

// Round 5
// 403.800 us; speedup vs baseline: 2.4471x; 1.1846x over previous
//
#include <hip/hip_runtime.h>
#include <hip/hip_bf16.h>

#define TPB 256
#define SH 6
#define BW 64  // nodes per bucket = 1<<SH; NBUK must be <= 1024 (N <= 65536)

// All edge/node kernels are batched over both graphs via blockIdx.y.

// ---------------- bucketed CSR build ----------------

// Per-block LDS histogram of dst buckets -> few global atomics.
__global__ void bucket_count_kernel(const int* __restrict__ dst0, const int* __restrict__ dst1,
                                    int E, int* __restrict__ bcnt, int nbuk) {
    const int* dst = blockIdx.y ? dst1 : dst0;
    int* bc = bcnt + blockIdx.y * 1024;
    __shared__ int hist[1024];
    for (int t = threadIdx.x; t < 1024; t += TPB) hist[t] = 0;
    __syncthreads();
    int base = blockIdx.x * 8192;
    int end = min(base + 8192, E);
    for (int e = base + (int)threadIdx.x; e < end; e += TPB)
        atomicAdd(&hist[dst[e] >> SH], 1);
    __syncthreads();
    for (int t = threadIdx.x; t < nbuk; t += TPB) {
        int h = hist[t];
        if (h) atomicAdd(&bc[t], h);
    }
}

// One block per graph: exclusive scan of bucket counts (nbuk <= 1024).
__global__ void bucket_scan_kernel(const int* __restrict__ bcnt, int nbuk,
                                   int* __restrict__ boff, int* __restrict__ bcur) {
    int g = blockIdx.x;
    const int* bc = bcnt + g * 1024;
    int* bo = boff + g * 1024;
    int* bu = bcur + g * 1024;
    __shared__ int s[1024];
    int t = threadIdx.x;
    int v = (t < nbuk) ? bc[t] : 0;
    s[t] = v;
    __syncthreads();
    for (int st = 1; st < 1024; st <<= 1) {
        int u = (t >= st) ? s[t - st] : 0;
        __syncthreads();
        s[t] += u;
        __syncthreads();
    }
    if (t < nbuk) { int e = s[t] - v; bo[t] = e; bu[t] = e; }
}

// Bin edges into bucket-contiguous regions of ebuf, packed (src<<SH)|(dst&63).
__global__ void bucket_scatter_kernel(const int* __restrict__ e0, const int* __restrict__ e1,
                                      int E, int* __restrict__ bcur,
                                      int* __restrict__ ebuf0, int* __restrict__ ebuf1, int nbuk) {
    int g = blockIdx.y;
    const int* src = g ? e1 : e0;
    const int* dst = src + E;
    int* ebuf = g ? ebuf1 : ebuf0;
    int* bu = bcur + g * 1024;
    __shared__ int hist[1024];
    for (int t = threadIdx.x; t < 1024; t += TPB) hist[t] = 0;
    __syncthreads();
    int base = blockIdx.x * 4096;
    int pk[16], bk[16], rk[16];
#pragma unroll
    for (int k = 0; k < 16; k++) {
        int e = base + k * TPB + (int)threadIdx.x;
        bk[k] = -1;
        if (e < E) {
            int s = src[e], d = dst[e];
            int b = d >> SH;
            bk[k] = b;
            pk[k] = (s << SH) | (d & (BW - 1));
            rk[k] = atomicAdd(&hist[b], 1);
        }
    }
    __syncthreads();
    for (int t = threadIdx.x; t < nbuk; t += TPB) {
        int h = hist[t];
        hist[t] = h ? atomicAdd(&bu[t], h) : 0;
    }
    __syncthreads();
#pragma unroll
    for (int k = 0; k < 16; k++)
        if (bk[k] >= 0) ebuf[hist[bk[k]] + rk[k]] = pk[k];
}

// Fused: per-bucket histogram -> local scan gives off/dinv directly
// (off[b*64 + t] = boff[b] + prefix of bucket-local counts), then fills col.
__global__ void bucket_csr_kernel(const int* __restrict__ ebuf0, const int* __restrict__ ebuf1,
                                  const int* __restrict__ boff, const int* __restrict__ bcnt,
                                  int n, int E,
                                  int* __restrict__ off0, int* __restrict__ off1,
                                  float* __restrict__ dinv0, float* __restrict__ dinv1,
                                  int* __restrict__ col0, int* __restrict__ col1) {
    int g = blockIdx.y;
    int b = blockIdx.x;
    const int* ebuf = g ? ebuf1 : ebuf0;
    int* off = g ? off1 : off0;
    float* dinv = g ? dinv1 : dinv0;
    int* col = g ? col1 : col0;
    __shared__ int h[BW], nb[BW], nrank[BW];
    int tid = threadIdx.x;
    if (tid < BW) h[tid] = 0;
    __syncthreads();
    int s = boff[g * 1024 + b], e = s + bcnt[g * 1024 + b];
    for (int i = s + tid; i < e; i += TPB)
        atomicAdd(&h[ebuf[i] & (BW - 1)], 1);
    __syncthreads();
    if (tid < BW) {
        int v = h[tid];
        int x = v;
        for (int d = 1; d < BW; d <<= 1) {
            int u = __shfl_up(x, d, 64);
            if (tid >= d) x += u;
        }
        int base = s + x - v;  // exclusive
        nb[tid] = base;
        nrank[tid] = 0;
        int node = b * BW + tid;
        if (node < n) {
            off[node] = base;
            dinv[node] = rsqrtf((float)v + 1.0f);
        }
        if (node == 0) off[n] = E;
    }
    __syncthreads();
    for (int i = s + tid; i < e; i += TPB) {
        int p = ebuf[i];
        int lo = p & (BW - 1);
        int r = atomicAdd(&nrank[lo], 1);
        col[nb[lo] + r] = p >> SH;
    }
}

// ---------------- dense matmul: Y[n,COUT] = dinv[n] * (X[n,CIN] @ W[CIN,COUT]) ----------

template <int CIN, int COUT, int TM>
__global__ void matmul_kernel(const float* __restrict__ X0, const float* __restrict__ X1,
                              const float* __restrict__ W,
                              const float* __restrict__ dinv0, const float* __restrict__ dinv1,
                              float* __restrict__ Y0, float* __restrict__ Y1, int n) {
    int g = blockIdx.y;
    const float* X = g ? X1 : X0;
    const float* dinv = g ? dinv1 : dinv0;
    float* Y = g ? Y1 : Y0;
    constexpr int G = COUT / 4;
    constexpr int S = 256 / G;
    constexpr int BN = S * TM;
    constexpr int XS = CIN + 1;
    constexpr int CH = CIN / 4;
    __shared__ float Xs[BN * XS];
    __shared__ float Ws[CIN * COUT];

    for (int i = threadIdx.x; i < CIN * COUT / 4; i += 256)
        ((float4*)Ws)[i] = ((const float4*)W)[i];
    int n0 = blockIdx.x * BN;
    for (int i = threadIdx.x; i < BN * CH; i += 256) {
        int nn = i / CH, kc = i % CH;
        float4 v = make_float4(0.f, 0.f, 0.f, 0.f);
        if (n0 + nn < n) v = *(const float4*)&X[(size_t)(n0 + nn) * CIN + 4 * kc];
        float* d = &Xs[nn * XS + 4 * kc];
        d[0] = v.x; d[1] = v.y; d[2] = v.z; d[3] = v.w;
    }
    __syncthreads();

    int cg = threadIdx.x % G;
    int slot = threadIdx.x / G;
    int c0 = cg * 4;
    float4 acc[TM];
#pragma unroll
    for (int i = 0; i < TM; i++) acc[i] = make_float4(0.f, 0.f, 0.f, 0.f);

    for (int k = 0; k < CIN; k++) {
        float4 b = *(const float4*)&Ws[k * COUT + c0];
#pragma unroll
        for (int i = 0; i < TM; i++) {
            float a = Xs[(slot * TM + i) * XS + k];
            acc[i].x += a * b.x;
            acc[i].y += a * b.y;
            acc[i].z += a * b.z;
            acc[i].w += a * b.w;
        }
    }
#pragma unroll
    for (int i = 0; i < TM; i++) {
        int node = n0 + slot * TM + i;
        if (node < n) {
            float d = dinv[node];
            float4 r = make_float4(acc[i].x * d, acc[i].y * d, acc[i].z * d, acc[i].w * d);
            *(float4*)&Y[(size_t)node * COUT + c0] = r;
        }
    }
}

// ---------------- GCN aggregation (gather over CSR-by-dst) ----------------
// HW pre-scaled by dinv_j. out[i,c] = act(dinv_i*(sum_j HW[j,c] + HW[i,c]) + b[c])

template <int C, bool RELU>
__device__ __forceinline__ float4 agg_node(const float* __restrict__ HW,
                                           const int* __restrict__ col,
                                           const float* __restrict__ bias,
                                           int node, int c0, int s, int e, float di) {
    float4 a0 = make_float4(0.f, 0.f, 0.f, 0.f);
    float4 a1 = make_float4(0.f, 0.f, 0.f, 0.f);
    int p = s;
    for (; p + 2 <= e; p += 2) {
        int j0 = col[p];
        int j1 = col[p + 1];
        float4 v0 = *(const float4*)&HW[(size_t)j0 * C + c0];
        float4 v1 = *(const float4*)&HW[(size_t)j1 * C + c0];
        a0.x += v0.x; a0.y += v0.y; a0.z += v0.z; a0.w += v0.w;
        a1.x += v1.x; a1.y += v1.y; a1.z += v1.z; a1.w += v1.w;
    }
    if (p < e) {
        int j = col[p];
        float4 v = *(const float4*)&HW[(size_t)j * C + c0];
        a0.x += v.x; a0.y += v.y; a0.z += v.z; a0.w += v.w;
    }
    float4 self = *(const float4*)&HW[(size_t)node * C + c0];
    float4 b4 = *(const float4*)&bias[c0];
    float4 r;
    r.x = di * (a0.x + a1.x + self.x) + b4.x;
    r.y = di * (a0.y + a1.y + self.y) + b4.y;
    r.z = di * (a0.z + a1.z + self.z) + b4.z;
    r.w = di * (a0.w + a1.w + self.w) + b4.w;
    if (RELU) {
        r.x = fmaxf(r.x, 0.f); r.y = fmaxf(r.y, 0.f);
        r.z = fmaxf(r.z, 0.f); r.w = fmaxf(r.w, 0.f);
    }
    return r;
}

template <int C, bool RELU>
__global__ void agg_kernel(const float* __restrict__ HW0, const float* __restrict__ HW1,
                           const int* __restrict__ off0, const int* __restrict__ off1,
                           const int* __restrict__ col0, const int* __restrict__ col1,
                           const float* __restrict__ dinv0, const float* __restrict__ dinv1,
                           const float* __restrict__ bias,
                           float* __restrict__ out0, float* __restrict__ out1, int n) {
    int g = blockIdx.y;
    const float* HW = g ? HW1 : HW0;
    const int* off = g ? off1 : off0;
    const int* col = g ? col1 : col0;
    const float* dinv = g ? dinv1 : dinv0;
    float* outp = g ? out1 : out0;
    constexpr int CH = C / 4;
    int tid = blockIdx.x * blockDim.x + threadIdx.x;
    int node = tid / CH;
    if (node >= n) return;
    int c0 = (tid % CH) * 4;
    float4 r = agg_node<C, RELU>(HW, col, bias, node, c0, off[node], off[node + 1], dinv[node]);
    *(float4*)&outp[(size_t)node * C + c0] = r;
}

// Layer-3 aggregation (C=16) with fused column-sum epilogue (for attention pooling).
__global__ void agg16_colsum_kernel(const float* __restrict__ HW0, const float* __restrict__ HW1,
                                    const int* __restrict__ off0, const int* __restrict__ off1,
                                    const int* __restrict__ col0, const int* __restrict__ col1,
                                    const float* __restrict__ dinv0, const float* __restrict__ dinv1,
                                    const float* __restrict__ bias,
                                    float* __restrict__ out0, float* __restrict__ out1,
                                    float* __restrict__ colsum, int n) {
    int g = blockIdx.y;
    const float* HW = g ? HW1 : HW0;
    const int* off = g ? off1 : off0;
    const int* col = g ? col1 : col0;
    const float* dinv = g ? dinv1 : dinv0;
    float* outp = g ? out1 : out0;
    int tid = blockIdx.x * blockDim.x + threadIdx.x;
    int node = tid / 4;
    int c0 = (tid % 4) * 4;
    float4 r = make_float4(0.f, 0.f, 0.f, 0.f);
    if (node < n) {
        r = agg_node<16, false>(HW, col, bias, node, c0, off[node], off[node + 1], dinv[node]);
        *(float4*)&outp[(size_t)node * 16 + c0] = r;
    }
    __shared__ float4 sd[TPB];
    sd[threadIdx.x] = r;
    __syncthreads();
    if (threadIdx.x < 64) {
        float4 a = sd[threadIdx.x], b = sd[threadIdx.x + 64],
               c = sd[threadIdx.x + 128], d = sd[threadIdx.x + 192];
        a.x += b.x + c.x + d.x; a.y += b.y + c.y + d.y;
        a.z += b.z + c.z + d.z; a.w += b.w + c.w + d.w;
        sd[threadIdx.x] = a;
    }
    __syncthreads();
    if (threadIdx.x < 4) {
        float4 a = make_float4(0.f, 0.f, 0.f, 0.f);
        for (int k = 0; k < 16; k++) {
            float4 v = sd[threadIdx.x + 4 * k];
            a.x += v.x; a.y += v.y; a.z += v.z; a.w += v.w;
        }
        float* cs = colsum + g * 16 + threadIdx.x * 4;
        atomicAdd(&cs[0], a.x);
        atomicAdd(&cs[1], a.y);
        atomicAdd(&cs[2], a.z);
        atomicAdd(&cs[3], a.w);
    }
}

// ---------------- attention pooling ----------------

__global__ void cvec_kernel(const float* __restrict__ colsum, const float* __restrict__ Wa,
                            float n_inv, float* __restrict__ cvec) {
    int g = blockIdx.x;
    int j = threadIdx.x;
    if (j < 16) {
        const float* cs = colsum + g * 16;
        float acc = 0.f;
        for (int i = 0; i < 16; i++) acc += (cs[i] * n_inv) * Wa[i * 16 + j];
        cvec[g * 16 + j] = tanhf(acc);
    }
}

__global__ void pool_kernel(const float* __restrict__ H0, const float* __restrict__ H1, int n,
                            const float* __restrict__ cvec, float* __restrict__ rep) {
    int g = blockIdx.y;
    const float* H = g ? H1 : H0;
    int c = threadIdx.x % 16;
    float cv = cvec[g * 16 + c];
    int w = (blockIdx.x * blockDim.x + threadIdx.x) / 16;
    int stride = (gridDim.x * blockDim.x) / 16;
    float acc = 0.f;
    for (int node = w; node < n; node += stride) {
        float x = H[(size_t)node * 16 + c];
        float p = x * cv;
        p += __shfl_xor(p, 1, 16);
        p += __shfl_xor(p, 2, 16);
        p += __shfl_xor(p, 4, 16);
        p += __shfl_xor(p, 8, 16);
        float s = 1.f / (1.f + __expf(-p));
        acc += s * x;
    }
    __shared__ float sdata[TPB];
    sdata[threadIdx.x] = acc;
    __syncthreads();
    if (threadIdx.x < 16) {
        float s = 0.f;
        for (int t = threadIdx.x; t < TPB; t += 16) s += sdata[t];
        atomicAdd(&rep[g * 16 + threadIdx.x], s);
    }
}

// ---------------- final tensor-network scoring ----------------

__global__ void final_kernel(const float* __restrict__ rep,
                             const float* __restrict__ Wt, const float* __restrict__ Wb,
                             const float* __restrict__ bt, const float* __restrict__ Wfc,
                             const float* __restrict__ bfc, const float* __restrict__ Wsc,
                             const float* __restrict__ bsc, float* __restrict__ out) {
    const float* e1 = rep;
    const float* e2 = rep + 16;
    __shared__ float scores[16], tvec[16], se1[16], se2[16];
    int t = threadIdx.x;
    if (t < 16) { se1[t] = e1[t]; se2[t] = e2[t]; }
    __syncthreads();
    if (t < 16) {
        float bil = 0.f;
        for (int i = 0; i < 16; i++) {
            float a = se1[i];
            for (int j = 0; j < 16; j++) bil += a * se2[j] * Wt[(i * 16 + j) * 16 + t];
        }
        float blk = 0.f;
        for (int m = 0; m < 16; m++)
            blk += Wb[t * 32 + m] * se1[m] + Wb[t * 32 + 16 + m] * se2[m];
        scores[t] = fmaxf(bil + blk + bt[t], 0.f);
    }
    __syncthreads();
    if (t < 16) {
        float acc = bfc[t];
        for (int k = 0; k < 16; k++) acc += scores[k] * Wfc[k * 16 + t];
        tvec[t] = tanhf(acc);
    }
    __syncthreads();
    if (t == 0) {
        float acc = bsc[0];
        for (int j = 0; j < 16; j++) acc += tvec[j] * Wsc[j];
        out[0] = 1.f / (1.f + __expf(-acc));
    }
}

// ---------------- launcher ----------------

extern "C" void kernel_launch(void* const* d_in, const int* in_sizes, int n_in,
                              void* d_out, int out_size, void* d_ws, size_t ws_size,
                              hipStream_t stream) {
    const float* X1 = (const float*)d_in[0];
    const float* X2 = (const float*)d_in[1];
    const int* edges1 = (const int*)d_in[2];
    const int* edges2 = (const int*)d_in[3];
    const float* W1 = (const float*)d_in[4];
    const float* b1 = (const float*)d_in[5];
    const float* W2 = (const float*)d_in[6];
    const float* b2 = (const float*)d_in[7];
    const float* W3 = (const float*)d_in[8];
    const float* b3 = (const float*)d_in[9];
    const float* Wa = (const float*)d_in[10];
    const float* Wt = (const float*)d_in[11];
    const float* Wb = (const float*)d_in[12];
    const float* bt = (const float*)d_in[13];
    const float* Wfc = (const float*)d_in[14];
    const float* bfc = (const float*)d_in[15];
    const float* Wsc = (const float*)d_in[16];
    const float* bsc = (const float*)d_in[17];
    float* out = (float*)d_out;

    const int N = in_sizes[0] / 96;
    const int E = in_sizes[2] / 2;
    const int NBUK = (N + BW - 1) / BW;  // buckets (must be <= 1024)

    // workspace layout (256B aligned chunks)
    char* ws = (char*)d_ws;
    size_t o = 0;
    auto alloc = [&](size_t bytes) {
        void* p = ws + o;
        o += (bytes + 255) & ~(size_t)255;
        return p;
    };
    // zero region: bcnt(2*1024 int) then small(96 float) — contiguous, one memset
    int* bcnt = (int*)alloc((size_t)2 * 1024 * 4);
    float* small = (float*)alloc(96 * 4);  // colsum[2*16] cvec[2*16] rep[2*16]
    float* colsum = small;
    float* cvec = small + 32;
    float* rep = small + 64;
    int* boff = (int*)alloc((size_t)2 * 1024 * 4);
    int* bcur = (int*)alloc((size_t)2 * 1024 * 4);
    int* off0 = (int*)alloc((size_t)(N + 1) * 4);
    int* off1 = (int*)alloc((size_t)(N + 1) * 4);
    int* col0 = (int*)alloc((size_t)E * 4);
    int* col1 = (int*)alloc((size_t)E * 4);
    float* dinv0 = (float*)alloc((size_t)N * 4);
    float* dinv1 = (float*)alloc((size_t)N * 4);
    float* bufA0 = (float*)alloc((size_t)N * 64 * 4);
    float* bufA1 = (float*)alloc((size_t)N * 64 * 4);
    float* bufB0 = (float*)alloc((size_t)N * 64 * 4);
    float* bufB1 = (float*)alloc((size_t)N * 64 * 4);
    int* ebuf0 = (int*)bufA0;  // ebuf dead before matmul first writes bufA
    int* ebuf1 = (int*)bufA1;

    const int gB1 = (E + 8191) / 8192;
    const int gB2 = (E + 4095) / 4096;

    // one memset zeroes bcnt + small (contiguous)
    hipMemsetAsync(bcnt, 0, (size_t)2 * 1024 * 4 + 96 * 4, stream);

    // bucketed CSR build (both graphs per dispatch)
    bucket_count_kernel<<<dim3(gB1, 2), TPB, 0, stream>>>(edges1 + E, edges2 + E, E, bcnt, NBUK);
    bucket_scan_kernel<<<2, 1024, 0, stream>>>(bcnt, NBUK, boff, bcur);
    bucket_scatter_kernel<<<dim3(gB2, 2), TPB, 0, stream>>>(edges1, edges2, E, bcur, ebuf0, ebuf1, NBUK);
    bucket_csr_kernel<<<dim3(NBUK, 2), TPB, 0, stream>>>(ebuf0, ebuf1, boff, bcnt, N, E,
                                                         off0, off1, dinv0, dinv1, col0, col1);

    // layer 1: 96 -> 64, agg + relu
    matmul_kernel<96, 64, 8><<<dim3((N + 127) / 128, 2), TPB, 0, stream>>>(X1, X2, W1, dinv0, dinv1, bufA0, bufA1, N);
    agg_kernel<64, true><<<dim3(((size_t)N * 16 + TPB - 1) / TPB, 2), TPB, 0, stream>>>(
        bufA0, bufA1, off0, off1, col0, col1, dinv0, dinv1, b1, bufB0, bufB1, N);
    // layer 2: 64 -> 32, agg + relu
    matmul_kernel<64, 32, 4><<<dim3((N + 127) / 128, 2), TPB, 0, stream>>>(bufB0, bufB1, W2, dinv0, dinv1, bufA0, bufA1, N);
    agg_kernel<32, true><<<dim3(((size_t)N * 8 + TPB - 1) / TPB, 2), TPB, 0, stream>>>(
        bufA0, bufA1, off0, off1, col0, col1, dinv0, dinv1, b2, bufB0, bufB1, N);
    // layer 3: 32 -> 16, agg (no relu) + fused column sums
    matmul_kernel<32, 16, 2><<<dim3((N + 127) / 128, 2), TPB, 0, stream>>>(bufB0, bufB1, W3, dinv0, dinv1, bufA0, bufA1, N);
    agg16_colsum_kernel<<<dim3(((size_t)N * 4 + TPB - 1) / TPB, 2), TPB, 0, stream>>>(
        bufA0, bufA1, off0, off1, col0, col1, dinv0, dinv1, b3, bufB0, bufB1, colsum, N);

    // attention pooling
    cvec_kernel<<<2, 64, 0, stream>>>(colsum, Wa, 1.0f / (float)N, cvec);
    pool_kernel<<<dim3(256, 2), TPB, 0, stream>>>(bufB0, bufB1, N, cvec, rep);

    final_kernel<<<1, 64, 0, stream>>>(rep, Wt, Wb, bt, Wfc, bfc, Wsc, bsc, out);
}